// Round 10
// baseline (144.502 us; speedup 1.0000x reference)
//
#include <hip/hip_runtime.h>
#include <math.h>

#define NTH 1024

typedef unsigned uint2v __attribute__((ext_vector_type(2)));
typedef float f32x2 __attribute__((ext_vector_type(2)));
typedef float f32x4 __attribute__((ext_vector_type(4)));

template <int CTRL>
__device__ __forceinline__ float dpp_mov(float x) {
  return __int_as_float(__builtin_amdgcn_mov_dpp(__float_as_int(x), CTRL, 0xF, 0xF, true));
}
__device__ __forceinline__ float row_sum16(float x) {
  x += dpp_mov<0x128>(x);   // row_ror:8
  x += dpp_mov<0x124>(x);   // row_ror:4
  x += dpp_mov<0x122>(x);   // row_ror:2
  x += dpp_mov<0x121>(x);   // row_ror:1
  return x;
}
__device__ __forceinline__ float row_max16(float x) {
  x = fmaxf(x, dpp_mov<0x128>(x));
  x = fmaxf(x, dpp_mov<0x124>(x));
  x = fmaxf(x, dpp_mov<0x122>(x));
  x = fmaxf(x, dpp_mov<0x121>(x));
  return x;
}
__device__ __forceinline__ float sum32(float x) {
  x = row_sum16(x);
  uint2v p = __builtin_amdgcn_permlane16_swap(__float_as_uint(x), __float_as_uint(x), false, false);
  return __uint_as_float(p.x) + __uint_as_float(p.y);
}
__device__ __forceinline__ float max32(float x) {
  x = row_max16(x);
  uint2v p = __builtin_amdgcn_permlane16_swap(__float_as_uint(x), __float_as_uint(x), false, false);
  return fmaxf(__uint_as_float(p.x), __uint_as_float(p.y));
}
__device__ __forceinline__ float sum_halves(float x) {
  uint2v p = __builtin_amdgcn_permlane32_swap(__float_as_uint(x), __float_as_uint(x), false, false);
  return __uint_as_float(p.x) + __uint_as_float(p.y);
}
__device__ __forceinline__ f32x2 sum_halves2(f32x2 v) {
  f32x2 r;
  r.x = sum_halves(v.x);
  r.y = sum_halves(v.y);
  return r;
}

__device__ __forceinline__ int swz8(int q, int c) { return (q + c) & 7; }

__global__ void
__launch_bounds__(NTH)
__attribute__((amdgpu_waves_per_eu(4, 4)))
convcaps_em_kernel(const float* __restrict__ x,
                   const float* __restrict__ wts,
                   const float* __restrict__ beta_u,
                   const float* __restrict__ beta_a,
                   float* __restrict__ out) {
  constexpr int BK = 288;
  constexpr float EPS = 1e-8f;
  constexpr float LAM = 1e-3f;

  __shared__ __align__(16) float v_lds[BK * 16];        // 18 KB
  __shared__ float w_lds[BK];                           // a/(a+eps)
  __shared__ __align__(8) float part_lds[32 * 32];      // colsum partials / M0 scratch
  __shared__ float rsum_lds[32];                        // M0 w-partials
  __shared__ __align__(16) float stage_lds[16 * 1024];  // 64 KB moment partials
  __shared__ __align__(16) float muinv2_lds[32 * 32];   // [c][swz(q)] quad={mu,mu,is,is}
  __shared__ float lnac_lds[32];
  __shared__ float mu0_lds[16], i2s0_lds[16], sc0_lds[2];

  const int t = threadIdx.x;
  const int n = blockIdx.x;
  const int b  = n >> 6;
  const int oy = (n >> 3) & 7;
  const int ox = n & 7;

  // ---------------- setup: w = a/(a+eps) and v = p_in @ w ----------------
  if (t < BK) {
    const int kk = t >> 5, cap = t & 31;
    const int kh = kk / 3, kw = kk - kh * 3;
    const int iy = oy * 2 - 1 + kh, ix = ox * 2 - 1 + kw;
    float val = 0.0f;
    if ((unsigned)iy < 16u && (unsigned)ix < 16u)
      val = x[(((b * 16 + iy) * 16) + ix) * 544 + 512 + cap];
    w_lds[t] = val / (val + EPS);
  }
  for (int task = t; task < BK * 4; task += NTH) {
    const int i = task >> 2, p = task & 3;
    const int kk = i >> 5, cap = i & 31;
    const int kh = kk / 3, kw = kk - kh * 3;
    const int iy = oy * 2 - 1 + kh, ix = ox * 2 - 1 + kw;
    float4 vv = make_float4(0.f, 0.f, 0.f, 0.f);
    if ((unsigned)iy < 16u && (unsigned)ix < 16u) {
      const float* px = x + ((((b * 16 + iy) * 16) + ix) * 544 + cap * 16 + p * 4);
      const float4 pin = *reinterpret_cast<const float4*>(px);
      const float* pw = wts + i * 16;
      const float4 w0 = *reinterpret_cast<const float4*>(pw + 0);
      const float4 w1 = *reinterpret_cast<const float4*>(pw + 4);
      const float4 w2 = *reinterpret_cast<const float4*>(pw + 8);
      const float4 w3 = *reinterpret_cast<const float4*>(pw + 12);
      vv.x = pin.x * w0.x + pin.y * w1.x + pin.z * w2.x + pin.w * w3.x;
      vv.y = pin.x * w0.y + pin.y * w1.y + pin.z * w2.y + pin.w * w3.y;
      vv.z = pin.x * w0.z + pin.y * w1.z + pin.z * w2.z + pin.w * w3.z;
      vv.w = pin.x * w0.w + pin.y * w1.w + pin.z * w2.w + pin.w * w3.w;
    }
    *reinterpret_cast<float4*>(&v_lds[i * 16 + p * 4]) = vv;
  }
  __syncthreads();

  const int c32 = t & 31;          // E: column
  const int g32 = t >> 5;          // E: row-group
  const int wv  = t >> 6;          // wave id
  const int ln  = t & 63;          // lane
  const int cS  = (t >> 4) & 31;   // stats: column
  const int pS  = t & 15;          // stats: p
  const float bu = beta_u[cS];
  const float ba = beta_a[cS];

  // ---------------- M0: it=0 m-step (r uniform => c-independent) ----------------
  if (t < 512) {
    const int h = t >> 4;
    float aw = 0.f, a1 = 0.f, a2 = 0.f;
    #pragma unroll
    for (int k = 0; k < 9; ++k) {
      const int i = h * 9 + k;
      const float wvv = w_lds[i];
      const float vv = v_lds[i * 16 + pS];
      aw += wvv;
      a1 = fmaf(wvv, vv, a1);
      a2 = fmaf(wvv * vv, vv, a2);
    }
    *reinterpret_cast<float2*>(&part_lds[(h * 16 + pS) * 2]) = make_float2(a1, a2);
    if (pS == 0) rsum_lds[h] = aw;
  }
  __syncthreads();
  if (t < 16) {
    float m0 = 0.f, a1 = 0.f, a2 = 0.f;
    #pragma unroll
    for (int h = 0; h < 32; ++h) {
      m0 += rsum_lds[h];
      const float2 f2 = *reinterpret_cast<const float2*>(&part_lds[(h * 16 + t) * 2]);
      a1 += f2.x; a2 += f2.y;
    }
    const float D0 = m0 + 32.f * EPS;
    const float mu = a1 / D0;
    float sig = (a2 - mu * (2.f * a1 - mu * m0)) / D0;
    sig = fmaxf(sig, 0.f) + EPS;
    const float ls = row_sum16(0.5f * __logf(sig));
    mu0_lds[t] = mu;
    i2s0_lds[t] = 0.5f / sig;
    if (t == 0) { sc0_lds[0] = m0 * 0.03125f; sc0_lds[1] = ls; }
  }
  __syncthreads();
  if (t < 512) {
    const int base = cS * 32 + (swz8(pS >> 1, cS) << 2);
    muinv2_lds[base + (pS & 1)] = mu0_lds[pS];
    muinv2_lds[base + 2 + (pS & 1)] = i2s0_lds[pS];
    if (pS == 0) {
      const float rs0 = sc0_lds[0], ls = sc0_lds[1];
      const float z = LAM * (ba - rs0 * (16.f * bu + ls));
      lnac_lds[cS] = -__logf(1.f + __expf(-z)) - ls;
    }
  }
  __syncthreads();

  // ---------------- 2 × (fused E + moments) + merged stats ----------------
  for (int it = 0; it < 2; ++it) {
    {
      f32x2 mu2[8], is2[8];
      #pragma unroll
      for (int q = 0; q < 8; ++q) {
        const f32x4 f =
            *reinterpret_cast<const f32x4*>(&muinv2_lds[c32 * 32 + (swz8(q, c32) << 2)]);
        mu2[q] = f.xy;
        is2[q] = f.zw;
      }
      const float lna = lnac_lds[c32];
      f32x2 s1v[8], s2v[8];
      #pragma unroll
      for (int q = 0; q < 8; ++q) {
        s1v[q] = f32x2{0.f, 0.f};
        s2v[q] = f32x2{0.f, 0.f};
      }
      float colsum = 0.f;

      // --- software-pipelined pass loop: load pass+1 before computing pass ---
      const float* vrow = &v_lds[g32 * 16];
      f32x4 c0 = *reinterpret_cast<const f32x4*>(vrow + 0);
      f32x4 c1 = *reinterpret_cast<const f32x4*>(vrow + 4);
      f32x4 c2 = *reinterpret_cast<const f32x4*>(vrow + 8);
      f32x4 c3 = *reinterpret_cast<const f32x4*>(vrow + 12);
      float wcur = w_lds[g32];
      #pragma unroll
      for (int pass = 0; pass < 9; ++pass) {
        // issue next pass's loads early (redundant reload of pass 0 on last iter)
        const int i_nxt = (pass < 8) ? ((pass + 1) * 32 + g32) : g32;
        const float* vnx = &v_lds[i_nxt * 16];
        const f32x4 n0 = *reinterpret_cast<const f32x4*>(vnx + 0);
        const f32x4 n1 = *reinterpret_cast<const f32x4*>(vnx + 4);
        const f32x4 n2 = *reinterpret_cast<const f32x4*>(vnx + 8);
        const f32x4 n3 = *reinterpret_cast<const f32x4*>(vnx + 12);
        const float wnxt = w_lds[i_nxt];

        f32x2 aa = f32x2{0.f, 0.f}, ab = f32x2{0.f, 0.f}, d;
        d = c0.xy - mu2[0]; aa = __builtin_elementwise_fma(d * d, is2[0], aa);
        d = c0.zw - mu2[1]; ab = __builtin_elementwise_fma(d * d, is2[1], ab);
        d = c1.xy - mu2[2]; aa = __builtin_elementwise_fma(d * d, is2[2], aa);
        d = c1.zw - mu2[3]; ab = __builtin_elementwise_fma(d * d, is2[3], ab);
        d = c2.xy - mu2[4]; aa = __builtin_elementwise_fma(d * d, is2[4], aa);
        d = c2.zw - mu2[5]; ab = __builtin_elementwise_fma(d * d, is2[5], ab);
        d = c3.xy - mu2[6]; aa = __builtin_elementwise_fma(d * d, is2[6], aa);
        d = c3.zw - mu2[7]; ab = __builtin_elementwise_fma(d * d, is2[7], ab);
        const f32x2 at = aa + ab;
        const float lnap = lna - (at.x + at.y);
        const float mx = max32(lnap);                 // per-row max (accuracy)
        const float e = __expf(lnap - mx);
        const float ss = sum32(e);                    // ss >= 1 (max lane gives e=1)
        const float rn = e * (wcur * __builtin_amdgcn_rcpf(ss));
        colsum += rn;
        f32x2 tv;
        tv = c0.xy * rn; s1v[0] += tv; s2v[0] = __builtin_elementwise_fma(tv, c0.xy, s2v[0]);
        tv = c0.zw * rn; s1v[1] += tv; s2v[1] = __builtin_elementwise_fma(tv, c0.zw, s2v[1]);
        tv = c1.xy * rn; s1v[2] += tv; s2v[2] = __builtin_elementwise_fma(tv, c1.xy, s2v[2]);
        tv = c1.zw * rn; s1v[3] += tv; s2v[3] = __builtin_elementwise_fma(tv, c1.zw, s2v[3]);
        tv = c2.xy * rn; s1v[4] += tv; s2v[4] = __builtin_elementwise_fma(tv, c2.xy, s2v[4]);
        tv = c2.zw * rn; s1v[5] += tv; s2v[5] = __builtin_elementwise_fma(tv, c2.zw, s2v[5]);
        tv = c3.xy * rn; s1v[6] += tv; s2v[6] = __builtin_elementwise_fma(tv, c3.xy, s2v[6]);
        tv = c3.zw * rn; s1v[7] += tv; s2v[7] = __builtin_elementwise_fma(tv, c3.zw, s2v[7]);

        c0 = n0; c1 = n1; c2 = n2; c3 = n3; wcur = wnxt;   // rotate pipeline regs
      }
      part_lds[g32 * 32 + c32] = colsum;
      #pragma unroll
      for (int q = 0; q < 8; ++q) {
        s1v[q] = sum_halves2(s1v[q]);
        s2v[q] = sum_halves2(s2v[q]);
      }
      float* srow = &stage_lds[wv * 1024 + c32 * 32];
      if (ln < 32) {
        f32x4 o;
        o.xy = s1v[0]; o.zw = s1v[1];
        *reinterpret_cast<f32x4*>(&srow[swz8(0, c32) << 2]) = o;
        o.xy = s1v[2]; o.zw = s1v[3];
        *reinterpret_cast<f32x4*>(&srow[swz8(1, c32) << 2]) = o;
        o.xy = s1v[4]; o.zw = s1v[5];
        *reinterpret_cast<f32x4*>(&srow[swz8(2, c32) << 2]) = o;
        o.xy = s1v[6]; o.zw = s1v[7];
        *reinterpret_cast<f32x4*>(&srow[swz8(3, c32) << 2]) = o;
      } else {
        f32x4 o;
        o.xy = s2v[0]; o.zw = s2v[1];
        *reinterpret_cast<f32x4*>(&srow[swz8(4, c32) << 2]) = o;
        o.xy = s2v[2]; o.zw = s2v[3];
        *reinterpret_cast<f32x4*>(&srow[swz8(5, c32) << 2]) = o;
        o.xy = s2v[4]; o.zw = s2v[5];
        *reinterpret_cast<f32x4*>(&srow[swz8(6, c32) << 2]) = o;
        o.xy = s2v[6]; o.zw = s2v[7];
        *reinterpret_cast<f32x4*>(&srow[swz8(7, c32) << 2]) = o;
      }
    }
    __syncthreads();

    // ---- merged gather + rsum + stats (one phase, one barrier) ----
    if (t < 512) {
      float rs = 0.f;
      #pragma unroll
      for (int g = 0; g < 32; ++g) rs += part_lds[g * 32 + cS];
      float gs1 = 0.f, gs2 = 0.f;
      const int off1 = cS * 32 + (swz8(pS >> 2, cS) << 2) + (pS & 3);
      const int off2 = cS * 32 + (swz8((pS >> 2) + 4, cS) << 2) + (pS & 3);
      #pragma unroll
      for (int w2 = 0; w2 < 16; ++w2) {
        gs1 += stage_lds[w2 * 1024 + off1];
        gs2 += stage_lds[w2 * 1024 + off2];
      }
      const float D = rs + EPS;
      const float mu = gs1 / D;
      float sig = (gs2 - mu * (2.f * gs1 - mu * rs)) / D;
      sig = fmaxf(sig, 0.f) + EPS;
      const float lsum = row_sum16(0.5f * __logf(sig));
      const float z = LAM * (ba - rs * (16.f * bu + lsum));
      if (it == 0) {
        const int base = cS * 32 + (swz8(pS >> 1, cS) << 2);
        muinv2_lds[base + (pS & 1)] = mu;
        muinv2_lds[base + 2 + (pS & 1)] = 0.5f / sig;
        if (pS == 0) lnac_lds[cS] = -__logf(1.f + __expf(-z)) - lsum;
      } else {
        out[n * 544 + t] = mu;
        if (pS == 0) out[n * 544 + 512 + cS] = 1.f / (1.f + __expf(-z));
      }
    }
    __syncthreads();
  }
}

extern "C" void kernel_launch(void* const* d_in, const int* in_sizes, int n_in,
                              void* d_out, int out_size, void* d_ws, size_t ws_size,
                              hipStream_t stream) {
  const float* x   = (const float*)d_in[0];
  const float* wts = (const float*)d_in[1];
  const float* bu  = (const float*)d_in[2];
  const float* ba  = (const float*)d_in[3];
  float* out = (float*)d_out;
  hipLaunchKernelGGL(convcaps_em_kernel, dim3(256), dim3(NTH), 0, stream,
                     x, wts, bu, ba, out);
}

// Round 11
// 79.315 us; speedup vs baseline: 1.8219x; 1.8219x over previous
//
#include <hip/hip_runtime.h>
#include <math.h>

#define NTH 1024

typedef unsigned uint2v __attribute__((ext_vector_type(2)));
typedef float f32x2 __attribute__((ext_vector_type(2)));
typedef float f32x4 __attribute__((ext_vector_type(4)));

template <int CTRL>
__device__ __forceinline__ float dpp_mov(float x) {
  return __int_as_float(__builtin_amdgcn_mov_dpp(__float_as_int(x), CTRL, 0xF, 0xF, true));
}
__device__ __forceinline__ float row_sum16(float x) {
  x += dpp_mov<0x128>(x);   // row_ror:8
  x += dpp_mov<0x124>(x);   // row_ror:4
  x += dpp_mov<0x122>(x);   // row_ror:2
  x += dpp_mov<0x121>(x);   // row_ror:1
  return x;
}
__device__ __forceinline__ float row_max16(float x) {
  x = fmaxf(x, dpp_mov<0x128>(x));
  x = fmaxf(x, dpp_mov<0x124>(x));
  x = fmaxf(x, dpp_mov<0x122>(x));
  x = fmaxf(x, dpp_mov<0x121>(x));
  return x;
}
__device__ __forceinline__ float sum32(float x) {
  x = row_sum16(x);
  uint2v p = __builtin_amdgcn_permlane16_swap(__float_as_uint(x), __float_as_uint(x), false, false);
  return __uint_as_float(p.x) + __uint_as_float(p.y);
}
__device__ __forceinline__ float max32(float x) {
  x = row_max16(x);
  uint2v p = __builtin_amdgcn_permlane16_swap(__float_as_uint(x), __float_as_uint(x), false, false);
  return fmaxf(__uint_as_float(p.x), __uint_as_float(p.y));
}
__device__ __forceinline__ float sum_halves(float x) {
  uint2v p = __builtin_amdgcn_permlane32_swap(__float_as_uint(x), __float_as_uint(x), false, false);
  return __uint_as_float(p.x) + __uint_as_float(p.y);
}
__device__ __forceinline__ f32x2 sum_halves2(f32x2 v) {
  f32x2 r;
  r.x = sum_halves(v.x);
  r.y = sum_halves(v.y);
  return r;
}

__device__ __forceinline__ int swz8(int q, int c) { return (q + c) & 7; }

__launch_bounds__(NTH, 4)
__global__ void convcaps_em_kernel(const float* __restrict__ x,
                                   const float* __restrict__ wts,
                                   const float* __restrict__ beta_u,
                                   const float* __restrict__ beta_a,
                                   float* __restrict__ out) {
  constexpr int BK = 288;
  constexpr float EPS = 1e-8f;
  constexpr float LAM = 1e-3f;

  __shared__ __align__(16) float v_lds[BK * 16];        // 18 KB
  __shared__ float w_lds[BK];                           // a/(a+eps)
  __shared__ __align__(8) float part_lds[32 * 32];      // colsum partials / M0 scratch
  __shared__ float rsum_lds[32];                        // M0 w-partials
  __shared__ __align__(16) float stage_lds[16 * 1024];  // 64 KB moment partials
  __shared__ __align__(16) float muinv2_lds[32 * 32];   // [c][swz(q)] quad={mu,mu,is,is}
  __shared__ float lnac_lds[32];
  __shared__ float mu0_lds[16], i2s0_lds[16], sc0_lds[2];

  const int t = threadIdx.x;
  const int n = blockIdx.x;
  const int b  = n >> 6;
  const int oy = (n >> 3) & 7;
  const int ox = n & 7;

  // ---------------- setup: w = a/(a+eps) and v = p_in @ w ----------------
  if (t < BK) {
    const int kk = t >> 5, cap = t & 31;
    const int kh = kk / 3, kw = kk - kh * 3;
    const int iy = oy * 2 - 1 + kh, ix = ox * 2 - 1 + kw;
    float val = 0.0f;
    if ((unsigned)iy < 16u && (unsigned)ix < 16u)
      val = x[(((b * 16 + iy) * 16) + ix) * 544 + 512 + cap];
    w_lds[t] = val / (val + EPS);
  }
  for (int task = t; task < BK * 4; task += NTH) {
    const int i = task >> 2, p = task & 3;
    const int kk = i >> 5, cap = i & 31;
    const int kh = kk / 3, kw = kk - kh * 3;
    const int iy = oy * 2 - 1 + kh, ix = ox * 2 - 1 + kw;
    float4 vv = make_float4(0.f, 0.f, 0.f, 0.f);
    if ((unsigned)iy < 16u && (unsigned)ix < 16u) {
      const float* px = x + ((((b * 16 + iy) * 16) + ix) * 544 + cap * 16 + p * 4);
      const float4 pin = *reinterpret_cast<const float4*>(px);
      const float* pw = wts + i * 16;
      const float4 w0 = *reinterpret_cast<const float4*>(pw + 0);
      const float4 w1 = *reinterpret_cast<const float4*>(pw + 4);
      const float4 w2 = *reinterpret_cast<const float4*>(pw + 8);
      const float4 w3 = *reinterpret_cast<const float4*>(pw + 12);
      vv.x = pin.x * w0.x + pin.y * w1.x + pin.z * w2.x + pin.w * w3.x;
      vv.y = pin.x * w0.y + pin.y * w1.y + pin.z * w2.y + pin.w * w3.y;
      vv.z = pin.x * w0.z + pin.y * w1.z + pin.z * w2.z + pin.w * w3.z;
      vv.w = pin.x * w0.w + pin.y * w1.w + pin.z * w2.w + pin.w * w3.w;
    }
    *reinterpret_cast<float4*>(&v_lds[i * 16 + p * 4]) = vv;
  }
  __syncthreads();

  const int c32 = t & 31;          // E: column
  const int g32 = t >> 5;          // E: row-group
  const int wv  = t >> 6;          // wave id
  const int ln  = t & 63;          // lane
  const int cS  = (t >> 4) & 31;   // stats: column
  const int pS  = t & 15;          // stats: p
  const float bu = beta_u[cS];
  const float ba = beta_a[cS];

  // ---------------- M0: it=0 m-step (r uniform => c-independent) ----------------
  if (t < 512) {
    const int h = t >> 4;
    float aw = 0.f, a1 = 0.f, a2 = 0.f;
    #pragma unroll
    for (int k = 0; k < 9; ++k) {
      const int i = h * 9 + k;
      const float wvv = w_lds[i];
      const float vv = v_lds[i * 16 + pS];
      aw += wvv;
      a1 = fmaf(wvv, vv, a1);
      a2 = fmaf(wvv * vv, vv, a2);
    }
    *reinterpret_cast<float2*>(&part_lds[(h * 16 + pS) * 2]) = make_float2(a1, a2);
    if (pS == 0) rsum_lds[h] = aw;
  }
  __syncthreads();
  if (t < 16) {
    float m0 = 0.f, a1 = 0.f, a2 = 0.f;
    #pragma unroll
    for (int h = 0; h < 32; ++h) {
      m0 += rsum_lds[h];
      const float2 f2 = *reinterpret_cast<const float2*>(&part_lds[(h * 16 + t) * 2]);
      a1 += f2.x; a2 += f2.y;
    }
    const float D0 = m0 + 32.f * EPS;
    const float mu = a1 / D0;
    float sig = (a2 - mu * (2.f * a1 - mu * m0)) / D0;
    sig = fmaxf(sig, 0.f) + EPS;
    const float ls = row_sum16(0.5f * __logf(sig));
    mu0_lds[t] = mu;
    i2s0_lds[t] = 0.5f / sig;
    if (t == 0) { sc0_lds[0] = m0 * 0.03125f; sc0_lds[1] = ls; }
  }
  __syncthreads();
  if (t < 512) {
    const int base = cS * 32 + (swz8(pS >> 1, cS) << 2);
    muinv2_lds[base + (pS & 1)] = mu0_lds[pS];
    muinv2_lds[base + 2 + (pS & 1)] = i2s0_lds[pS];
    if (pS == 0) {
      const float rs0 = sc0_lds[0], ls = sc0_lds[1];
      const float z = LAM * (ba - rs0 * (16.f * bu + ls));
      lnac_lds[cS] = -__logf(1.f + __expf(-z)) - ls;
    }
  }
  __syncthreads();

  // ---------------- 2 × (fused E + moments) + merged stats ----------------
  for (int it = 0; it < 2; ++it) {
    {
      f32x2 mu2[8], is2[8];
      #pragma unroll
      for (int q = 0; q < 8; ++q) {
        const f32x4 f =
            *reinterpret_cast<const f32x4*>(&muinv2_lds[c32 * 32 + (swz8(q, c32) << 2)]);
        mu2[q] = f.xy;
        is2[q] = f.zw;
      }
      const float lna = lnac_lds[c32];
      f32x2 s1v[8], s2v[8];
      #pragma unroll
      for (int q = 0; q < 8; ++q) {
        s1v[q] = f32x2{0.f, 0.f};
        s2v[q] = f32x2{0.f, 0.f};
      }
      float colsum = 0.f;
      #pragma unroll 3
      for (int pass = 0; pass < 9; ++pass) {
        const int i = pass * 32 + g32;
        const f32x4 q0 = *reinterpret_cast<const f32x4*>(&v_lds[i * 16 + 0]);
        const f32x4 q1 = *reinterpret_cast<const f32x4*>(&v_lds[i * 16 + 4]);
        const f32x4 q2 = *reinterpret_cast<const f32x4*>(&v_lds[i * 16 + 8]);
        const f32x4 q3 = *reinterpret_cast<const f32x4*>(&v_lds[i * 16 + 12]);
        f32x2 aa = f32x2{0.f, 0.f}, ab = f32x2{0.f, 0.f}, d;
        d = q0.xy - mu2[0]; aa = __builtin_elementwise_fma(d * d, is2[0], aa);
        d = q0.zw - mu2[1]; ab = __builtin_elementwise_fma(d * d, is2[1], ab);
        d = q1.xy - mu2[2]; aa = __builtin_elementwise_fma(d * d, is2[2], aa);
        d = q1.zw - mu2[3]; ab = __builtin_elementwise_fma(d * d, is2[3], ab);
        d = q2.xy - mu2[4]; aa = __builtin_elementwise_fma(d * d, is2[4], aa);
        d = q2.zw - mu2[5]; ab = __builtin_elementwise_fma(d * d, is2[5], ab);
        d = q3.xy - mu2[6]; aa = __builtin_elementwise_fma(d * d, is2[6], aa);
        d = q3.zw - mu2[7]; ab = __builtin_elementwise_fma(d * d, is2[7], ab);
        const f32x2 at = aa + ab;
        const float lnap = lna - (at.x + at.y);
        const float mx = max32(lnap);                 // per-row max (accuracy)
        const float e = __expf(lnap - mx);
        const float ss = sum32(e);                    // ss >= 1 (max lane gives e=1)
        const float rn = e * (w_lds[i] * __builtin_amdgcn_rcpf(ss));
        colsum += rn;
        f32x2 tv;
        tv = q0.xy * rn; s1v[0] += tv; s2v[0] = __builtin_elementwise_fma(tv, q0.xy, s2v[0]);
        tv = q0.zw * rn; s1v[1] += tv; s2v[1] = __builtin_elementwise_fma(tv, q0.zw, s2v[1]);
        tv = q1.xy * rn; s1v[2] += tv; s2v[2] = __builtin_elementwise_fma(tv, q1.xy, s2v[2]);
        tv = q1.zw * rn; s1v[3] += tv; s2v[3] = __builtin_elementwise_fma(tv, q1.zw, s2v[3]);
        tv = q2.xy * rn; s1v[4] += tv; s2v[4] = __builtin_elementwise_fma(tv, q2.xy, s2v[4]);
        tv = q2.zw * rn; s1v[5] += tv; s2v[5] = __builtin_elementwise_fma(tv, q2.zw, s2v[5]);
        tv = q3.xy * rn; s1v[6] += tv; s2v[6] = __builtin_elementwise_fma(tv, q3.xy, s2v[6]);
        tv = q3.zw * rn; s1v[7] += tv; s2v[7] = __builtin_elementwise_fma(tv, q3.zw, s2v[7]);
      }
      part_lds[g32 * 32 + c32] = colsum;
      #pragma unroll
      for (int q = 0; q < 8; ++q) {
        s1v[q] = sum_halves2(s1v[q]);
        s2v[q] = sum_halves2(s2v[q]);
      }
      float* srow = &stage_lds[wv * 1024 + c32 * 32];
      if (ln < 32) {
        f32x4 o;
        o.xy = s1v[0]; o.zw = s1v[1];
        *reinterpret_cast<f32x4*>(&srow[swz8(0, c32) << 2]) = o;
        o.xy = s1v[2]; o.zw = s1v[3];
        *reinterpret_cast<f32x4*>(&srow[swz8(1, c32) << 2]) = o;
        o.xy = s1v[4]; o.zw = s1v[5];
        *reinterpret_cast<f32x4*>(&srow[swz8(2, c32) << 2]) = o;
        o.xy = s1v[6]; o.zw = s1v[7];
        *reinterpret_cast<f32x4*>(&srow[swz8(3, c32) << 2]) = o;
      } else {
        f32x4 o;
        o.xy = s2v[0]; o.zw = s2v[1];
        *reinterpret_cast<f32x4*>(&srow[swz8(4, c32) << 2]) = o;
        o.xy = s2v[2]; o.zw = s2v[3];
        *reinterpret_cast<f32x4*>(&srow[swz8(5, c32) << 2]) = o;
        o.xy = s2v[4]; o.zw = s2v[5];
        *reinterpret_cast<f32x4*>(&srow[swz8(6, c32) << 2]) = o;
        o.xy = s2v[6]; o.zw = s2v[7];
        *reinterpret_cast<f32x4*>(&srow[swz8(7, c32) << 2]) = o;
      }
    }
    __syncthreads();

    // ---- merged gather + rsum + stats (one phase, one barrier) ----
    if (t < 512) {
      float rs = 0.f;
      #pragma unroll
      for (int g = 0; g < 32; ++g) rs += part_lds[g * 32 + cS];
      float gs1 = 0.f, gs2 = 0.f;
      const int off1 = cS * 32 + (swz8(pS >> 2, cS) << 2) + (pS & 3);
      const int off2 = cS * 32 + (swz8((pS >> 2) + 4, cS) << 2) + (pS & 3);
      #pragma unroll
      for (int w2 = 0; w2 < 16; ++w2) {
        gs1 += stage_lds[w2 * 1024 + off1];
        gs2 += stage_lds[w2 * 1024 + off2];
      }
      const float D = rs + EPS;
      const float mu = gs1 / D;
      float sig = (gs2 - mu * (2.f * gs1 - mu * rs)) / D;
      sig = fmaxf(sig, 0.f) + EPS;
      const float lsum = row_sum16(0.5f * __logf(sig));
      const float z = LAM * (ba - rs * (16.f * bu + lsum));
      if (it == 0) {
        const int base = cS * 32 + (swz8(pS >> 1, cS) << 2);
        muinv2_lds[base + (pS & 1)] = mu;
        muinv2_lds[base + 2 + (pS & 1)] = 0.5f / sig;
        if (pS == 0) lnac_lds[cS] = -__logf(1.f + __expf(-z)) - lsum;
      } else {
        out[n * 544 + t] = mu;
        if (pS == 0) out[n * 544 + 512 + cS] = 1.f / (1.f + __expf(-z));
      }
    }
    __syncthreads();
  }
}

extern "C" void kernel_launch(void* const* d_in, const int* in_sizes, int n_in,
                              void* d_out, int out_size, void* d_ws, size_t ws_size,
                              hipStream_t stream) {
  const float* x   = (const float*)d_in[0];
  const float* wts = (const float*)d_in[1];
  const float* bu  = (const float*)d_in[2];
  const float* ba  = (const float*)d_in[3];
  float* out = (float*)d_out;
  hipLaunchKernelGGL(convcaps_em_kernel, dim3(256), dim3(NTH), 0, stream,
                     x, wts, bu, ba, out);
}